// Round 4
// baseline (4764.623 us; speedup 1.0000x reference)
//
#include <hip/hip_runtime.h>
#include <hip/hip_bf16.h>

#define B_TOT 2048
#define L_SEQ 2048
#define NBLK  256
#define BQ    8
#define NWAVE 8
#define XBS   454   // ushorts per XB row = 227 dwords (odd -> bank spread)
#define H0RAW 0     // raw h0 double-buffer   [0,128)
#define H1M   128   // masked h1 double-buffer [128,256)
#define XOFF  256   // x5 double-buffer        [256,320)
#define H0M   320   // masked h0 double-buffer [320,448)

typedef __attribute__((ext_vector_type(8))) short bf16x8;
typedef __attribute__((ext_vector_type(4))) float f32x4;

#if __has_builtin(__builtin_amdgcn_exp2f)
static __device__ __forceinline__ float fexp2(float x){ return __builtin_amdgcn_exp2f(x); }
#else
static __device__ __forceinline__ float fexp2(float x){ return exp2f(x); }
#endif
#if __has_builtin(__builtin_amdgcn_rcpf)
static __device__ __forceinline__ float frcp (float x){ return __builtin_amdgcn_rcpf(x); }
#else
static __device__ __forceinline__ float frcp (float x){ return 1.0f / x; }
#endif

static __device__ __forceinline__ unsigned short f2bf(float f){
  union { float f; unsigned int u; } v; v.f = f;
  unsigned int u = v.u;
  u += 0x7FFFu + ((u >> 16) & 1u);      // RTNE
  return (unsigned short)(u >> 16);
}
// pack bf16(a) into both halves (RTNE); low-half write is order-immune
static __device__ __forceinline__ unsigned int cvtpk2(float a){
  unsigned int r;
  asm("v_cvt_pk_bf16_f32 %0, %1, %2" : "=v"(r) : "v"(a), "v"(a));
  return r;
}

static __device__ __forceinline__ float sigm_pre(float x, float bpre){
  return frcp(1.f + fexp2(__builtin_fmaf(x, -1.4426950408889634f, bpre)));
}
static __device__ __forceinline__ float tanh_pre(float x, float bpre){
  return 1.f - 2.f*frcp(1.f + fexp2(__builtin_fmaf(x, 2.8853900817779268f, bpre)));
}
static __device__ __forceinline__ float cell_act(float gi,float gf,float gg,float go,
    float bi,float bf,float bg,float bo, float& c, bool act){
  float is = sigm_pre(gi, bi);
  float fs = sigm_pre(gf, bf);
  float gt = tanh_pre(gg, bg);
  float os = sigm_pre(go, bo);
  float cn = __builtin_fmaf(fs, c, is*gt);
  float h  = os * tanh_pre(cn, 0.f);
  c = act ? cn : 0.f;                    // carried c = where(active, c', 0)
  return h;                              // RAW h (mask applied at store)
}

__global__ __launch_bounds__(512, 1)
void dh_lstm(const float* __restrict__ dP, const float* __restrict__ eps,
             const float* __restrict__ Wih0, const float* __restrict__ Whh0,
             const float* __restrict__ bih0, const float* __restrict__ bhh0,
             const float* __restrict__ Wih1, const float* __restrict__ Whh1,
             const float* __restrict__ bih1, const float* __restrict__ bhh1,
             const float* __restrict__ Whead, const float* __restrict__ bhead_p,
             const int* __restrict__ lengths, const int* __restrict__ revp,
             float* __restrict__ out)
{
  __shared__ unsigned short XB[16][XBS];
  __shared__ float dpart2[8][8];   // [batch col][wave]

  const int tid = threadIdx.x;
  const int l   = tid & 63;
  const int w   = tid >> 6;        // wave id: owns hidden units [8w, 8w+8)
  const int g   = l >> 4;          // lanegroup
  const int r16 = l & 15;
  const int r8  = r16 & 7;         // real batch slot
  const int hb  = r16 >> 3;        // 0: unit 2g+0, 1: unit 2g+1
  const int b0  = blockIdx.x * BQ;
  const int rev = revp[0];

  { // zero LDS (rows 8-15 must stay zero: they are the MFMA N-padding)
    unsigned int* p = (unsigned int*)&XB[0][0];
    for (int i = tid; i < 16*XBS/2; i += 512) p[i] = 0u;
  }

  // ---- weights -> registers as MFMA A-fragments (permuted gate rows) ----
  // wave-w rows p in [32w,32w+32): tile tau=t1, in-tile row = 2u + t0,
  // gate t = 2*tau + t0, source row j = 64*t + 8*w + u.
  bf16x8 A0[2][3], A1[2][4];
  {
    const int u  = r16 >> 1;
    const int t0 = r16 & 1;
#pragma unroll
    for (int tau = 0; tau < 2; ++tau){
      const int j = 64*(2*tau + t0) + 8*w + u;
#pragma unroll
      for (int k = 0; k < 3; ++k){      // L0: [Whh0(64) | Wih0 cols 0..5 | 0pad]
        bf16x8 a;
#pragma unroll
        for (int e = 0; e < 8; ++e){
          const int c = 32*k + 8*g + e;
          float v = 0.f;
          if (c < 64) v = Whh0[j*64 + c];
          else if (c < 70) v = Wih0[j*6 + (c-64)];
          a[e] = (short)f2bf(v);
        }
        A0[tau][k] = a;
      }
#pragma unroll
      for (int k = 0; k < 4; ++k){      // L1: [Wih1(64) | Whh1(64)]
        bf16x8 a;
#pragma unroll
        for (int e = 0; e < 8; ++e){
          const int c = 32*k + 8*g + e;
          const float v = (c < 64) ? Wih1[j*64 + c] : Whh1[j*64 + (c-64)];
          a[e] = (short)f2bf(v);
        }
        A1[tau][k] = a;
      }
    }
  }

  // act-side per-lane constants: this lane's unit = 8w + 2g + hb
  const int ju = 8*w + 2*g + hb;
  float bp0v[4], bp1v[4], wxv[4];
#pragma unroll
  for (int t4 = 0; t4 < 4; ++t4){
    const int jj = 64*t4 + ju;
    const float sc = (t4 == 2) ? 2.8853900817779268f : -1.4426950408889634f;
    bp0v[t4] = sc * (bih0[jj] + bhh0[jj]);
    bp1v[t4] = sc * (bih1[jj] + bhh1[jj]);
    wxv[t4]  = Wih0[jj*6 + 5];     // h_d column of W_ih0 (done on VALU)
  }
  const float wh    = Whead[ju];
  const float bhead = bhead_p[0];
  const int   lenb  = lengths[b0 + r8];

  __syncthreads();

  // x prefetch pipeline: x(t) lives in buf t&1; wave1 lanes 0..7 manage it.
  float xr0=0,xr1=0,xr2=0,xr3=0,xr4=0;
  const bool xload = (w == 1) && (l < 8);
  if (xload){
    const int t0p = rev ? (L_SEQ-1) : 0;
    const float4 v = *(const float4*)(dP + ((size_t)(b0+l)*L_SEQ + t0p)*4);
    const float ev = eps[(size_t)(b0+l)*L_SEQ + t0p];
    unsigned int* dst = (unsigned int*)&XB[l][XOFF];
    dst[0] = (unsigned int)f2bf(v.x) | ((unsigned int)f2bf(v.y) << 16);
    dst[1] = (unsigned int)f2bf(v.z) | ((unsigned int)f2bf(v.w) << 16);
    XB[l][XOFF+4] = f2bf(ev);
    const int t1p = rev ? (L_SEQ-2) : 1;
    const float4 v1 = *(const float4*)(dP + ((size_t)(b0+l)*L_SEQ + t1p)*4);
    xr0=v1.x; xr1=v1.y; xr2=v1.z; xr3=v1.w;
    xr4 = eps[(size_t)(b0+l)*L_SEQ + t1p];
  }
  __syncthreads();

  float c0s=0.f, c1s=0.f, h_d=0.f;
  const unsigned short* Brow = &XB[r16][0];

  for (int t = 0; t < L_SEQ; ++t){
    const int par = t & 1;
    const int tp  = rev ? (L_SEQ-1-t) : t;
    const bool act = tp < lenb;

    // ---- P1: L0 MFMAs + hh1 half of L1 (uses masked prev-state buffers) ----
    f32x4 acc0a={0,0,0,0}, acc0b={0,0,0,0}, acc1a={0,0,0,0}, acc1b={0,0,0,0};
    {
      const int hbuf = 64*(par^1);
      bf16x8 bk0 = *(const bf16x8*)(Brow + H0M + hbuf + 8*g);
      bf16x8 bk1 = *(const bf16x8*)(Brow + H0M + hbuf + 32 + 8*g);
      bf16x8 bx  = *(const bf16x8*)(Brow + XOFF + 32*par + 8*g);
      bf16x8 bh2 = *(const bf16x8*)(Brow + H1M + hbuf + 8*g);
      bf16x8 bh3 = *(const bf16x8*)(Brow + H1M + hbuf + 32 + 8*g);
      acc0a = __builtin_amdgcn_mfma_f32_16x16x32_bf16(A0[0][0], bk0, acc0a,0,0,0);
      acc0b = __builtin_amdgcn_mfma_f32_16x16x32_bf16(A0[1][0], bk0, acc0b,0,0,0);
      acc0a = __builtin_amdgcn_mfma_f32_16x16x32_bf16(A0[0][1], bk1, acc0a,0,0,0);
      acc0b = __builtin_amdgcn_mfma_f32_16x16x32_bf16(A0[1][1], bk1, acc0b,0,0,0);
      acc0a = __builtin_amdgcn_mfma_f32_16x16x32_bf16(A0[0][2], bx,  acc0a,0,0,0);
      acc0b = __builtin_amdgcn_mfma_f32_16x16x32_bf16(A0[1][2], bx,  acc0b,0,0,0);
      acc1a = __builtin_amdgcn_mfma_f32_16x16x32_bf16(A1[0][2], bh2, acc1a,0,0,0);
      acc1b = __builtin_amdgcn_mfma_f32_16x16x32_bf16(A1[1][2], bh2, acc1b,0,0,0);
      acc1a = __builtin_amdgcn_mfma_f32_16x16x32_bf16(A1[0][3], bh3, acc1a,0,0,0);
      acc1b = __builtin_amdgcn_mfma_f32_16x16x32_bf16(A1[1][3], bh3, acc1b,0,0,0);
    }
    // ---- P2: redistribute L0 gates to lane pairs, 1 cell_act/lane ----
    {
      const float xi = __shfl_xor(acc0a[2], 8);
      const float xf = __shfl_xor(acc0a[3], 8);
      const float xg = __shfl_xor(acc0b[2], 8);
      const float xo = __shfl_xor(acc0b[3], 8);
      float gi = hb ? xi : acc0a[0];
      float gf = hb ? xf : acc0a[1];
      float gg = hb ? xg : acc0b[0];
      float go = hb ? xo : acc0b[1];
      gi = __builtin_fmaf(wxv[0], h_d, gi);
      gf = __builtin_fmaf(wxv[1], h_d, gf);
      gg = __builtin_fmaf(wxv[2], h_d, gg);
      go = __builtin_fmaf(wxv[3], h_d, go);
      const float h0v = cell_act(gi,gf,gg,go, bp0v[0],bp0v[1],bp0v[2],bp0v[3], c0s, act);
      const unsigned int rr = cvtpk2(h0v);
      const unsigned int rm = act ? rr : 0u;
      XB[r8][H0RAW + 64*par + ju] = (unsigned short)rr;   // raw: within-step ih1
      XB[r8][H0M   + 64*par + ju] = (unsigned short)rm;   // masked: next-step carry
      if (xload){
        unsigned int* dst = (unsigned int*)&XB[l][XOFF + 32*(par^1)];
        dst[0] = (unsigned int)f2bf(xr0) | ((unsigned int)f2bf(xr1) << 16);
        dst[1] = (unsigned int)f2bf(xr2) | ((unsigned int)f2bf(xr3) << 16);
        XB[l][XOFF + 32*(par^1) + 4] = f2bf(xr4);
        int ts = t + 2;
        int tpn = rev ? (L_SEQ-1-ts) : ts;
        tpn = tpn < 0 ? 0 : (tpn >= L_SEQ ? L_SEQ-1 : tpn);
        const float4 v = *(const float4*)(dP + ((size_t)(b0+l)*L_SEQ + tpn)*4);
        xr0=v.x; xr1=v.y; xr2=v.z; xr3=v.w;
        xr4 = eps[(size_t)(b0+l)*L_SEQ + tpn];
      }
    }
    __syncthreads();   // B2: raw h0(t) + x(t+1) visible
    // ---- P3: ih1 half of L1 (needs raw h0(t)) ----
    {
      bf16x8 bk0 = *(const bf16x8*)(Brow + H0RAW + 64*par + 8*g);
      bf16x8 bk1 = *(const bf16x8*)(Brow + H0RAW + 64*par + 32 + 8*g);
      acc1a = __builtin_amdgcn_mfma_f32_16x16x32_bf16(A1[0][0], bk0, acc1a,0,0,0);
      acc1b = __builtin_amdgcn_mfma_f32_16x16x32_bf16(A1[1][0], bk0, acc1b,0,0,0);
      acc1a = __builtin_amdgcn_mfma_f32_16x16x32_bf16(A1[0][1], bk1, acc1a,0,0,0);
      acc1b = __builtin_amdgcn_mfma_f32_16x16x32_bf16(A1[1][1], bk1, acc1b,0,0,0);
    }
    // ---- P4: L1 gates redistribute + act, masked h1 store, head reduce ----
    {
      const float xi = __shfl_xor(acc1a[2], 8);
      const float xf = __shfl_xor(acc1a[3], 8);
      const float xg = __shfl_xor(acc1b[2], 8);
      const float xo = __shfl_xor(acc1b[3], 8);
      const float gi = hb ? xi : acc1a[0];
      const float gf = hb ? xf : acc1a[1];
      const float gg = hb ? xg : acc1b[0];
      const float go = hb ? xo : acc1b[1];
      const float h1v = cell_act(gi,gf,gg,go, bp1v[0],bp1v[1],bp1v[2],bp1v[3], c1s, act);
      const unsigned int rr = cvtpk2(h1v);
      const unsigned int rm = act ? rr : 0u;
      XB[r8][H1M + 64*par + ju] = (unsigned short)rm;     // masked carry
      float s = wh * h1v;                                  // head uses RAW h1
      s += __shfl_xor(s, 8);
      s += __shfl_xor(s, 16);
      s += __shfl_xor(s, 32);
      if (l < 8) dpart2[l][w] = s;
    }
    __syncthreads();   // B4: masked h1(t) + dpart visible
    // ---- P5: delta, h_d update (replicated), outputs ----
    {
      const f32x4 dp0 = *(const f32x4*)&dpart2[r8][0];
      const f32x4 dp1 = *(const f32x4*)&dpart2[r8][4];
      const float dsum = bhead + ((dp0[0]+dp0[1])+(dp0[2]+dp0[3]))
                               + ((dp1[0]+dp1[1])+(dp1[2]+dp1[3]));
      const float h_prev = h_d;
      if (act) h_d += dsum;            // where(active, h_d+delta, h_d)
      if (w == 0 && l < 8){
        const int bi = b0 + l;
        out[(size_t)bi*L_SEQ + tp] = h_prev;                                // h_seq
        out[(size_t)B_TOT*L_SEQ + (size_t)bi*L_SEQ + tp] = dsum;            // d_seq
      }
    }
  }
}

extern "C" void kernel_launch(void* const* d_in, const int* in_sizes, int n_in,
                              void* d_out, int out_size, void* d_ws, size_t ws_size,
                              hipStream_t stream) {
  (void)in_sizes; (void)n_in; (void)d_ws; (void)ws_size; (void)out_size;
  dh_lstm<<<dim3(NBLK), dim3(512), 0, stream>>>(
      (const float*)d_in[0],  (const float*)d_in[1],
      (const float*)d_in[2],  (const float*)d_in[3],
      (const float*)d_in[4],  (const float*)d_in[5],
      (const float*)d_in[6],  (const float*)d_in[7],
      (const float*)d_in[8],  (const float*)d_in[9],
      (const float*)d_in[10], (const float*)d_in[11],
      (const int*)d_in[12],   (const int*)d_in[13],
      (float*)d_out);
}

// Round 6
// 2276.625 us; speedup vs baseline: 2.0928x; 2.0928x over previous
//
#include <hip/hip_runtime.h>
#include <hip/hip_bf16.h>

#define B_TOT 2048
#define L_SEQ 2048
#define NBLK  256
#define BQ    8
#define NWAVE 8
#define XBS   328   // ushorts per XB row: 656B = 16B-aligned, 164 dwords (mod 32 = 4 stagger)

typedef __attribute__((ext_vector_type(8))) short bf16x8;
typedef __attribute__((ext_vector_type(4))) float f32x4;

#if __has_builtin(__builtin_amdgcn_exp2f)
static __device__ __forceinline__ float fexp2(float x){ return __builtin_amdgcn_exp2f(x); }
#else
static __device__ __forceinline__ float fexp2(float x){ return exp2f(x); }
#endif
#if __has_builtin(__builtin_amdgcn_rcpf)
static __device__ __forceinline__ float frcp (float x){ return __builtin_amdgcn_rcpf(x); }
#else
static __device__ __forceinline__ float frcp (float x){ return 1.0f / x; }
#endif

static __device__ __forceinline__ unsigned short f2bf(float f){
  union { float f; unsigned int u; } v; v.f = f;
  unsigned int u = v.u;
  u += 0x7FFFu + ((u >> 16) & 1u);      // RTNE
  return (unsigned short)(u >> 16);
}
// pack bf16(a) low | bf16(b) high in one instruction (RTNE)
static __device__ __forceinline__ unsigned int cvtpk(float a, float b){
  unsigned int r;
  asm("v_cvt_pk_bf16_f32 %0, %1, %2" : "=v"(r) : "v"(a), "v"(b));
  return r;
}

static __device__ __forceinline__ float sigm_pre(float x, float bpre){
  // sigmoid(x + bias), bpre = -log2(e)*bias
  return frcp(1.f + fexp2(__builtin_fmaf(x, -1.4426950408889634f, bpre)));
}
static __device__ __forceinline__ float tanh_pre(float x, float bpre){
  // tanh(x + bias), bpre = 2*log2(e)*bias
  return 1.f - 2.f*frcp(1.f + fexp2(__builtin_fmaf(x, 2.8853900817779268f, bpre)));
}
static __device__ __forceinline__ float cell_act(float gi,float gf,float gg,float go,
    float bi,float bf,float bg,float bo, float& c, bool act){
  float is = sigm_pre(gi, bi);
  float fs = sigm_pre(gf, bf);
  float gt = tanh_pre(gg, bg);
  float os = sigm_pre(go, bo);
  float cn = __builtin_fmaf(fs, c, is*gt);
  float h  = os * tanh_pre(cn, 0.f);
  c = act ? cn : 0.f;                    // new_cs = where(active, c', 0)
  return h;                              // RAW h (masking done at next-step read)
}
static __device__ __forceinline__ bf16x8 maskz(bf16x8 v, bool keep){
  union { bf16x8 v; unsigned int u[4]; } x; x.v = v;
  unsigned int m = keep ? 0xFFFFFFFFu : 0u;
  x.u[0]&=m; x.u[1]&=m; x.u[2]&=m; x.u[3]&=m;
  return x.v;
}

// XB row layout (per batch-slot b, ushort cols):
//   [  0..127) h0 double-buffer (64 per buf)
//   [128..255) h1 double-buffer
//   [256..319) x5 double-buffer (32 per buf: dP0..3, eps, zeros)
__global__ __launch_bounds__(512, 2)
void dh_lstm(const float* __restrict__ dP, const float* __restrict__ eps,
             const float* __restrict__ Wih0, const float* __restrict__ Whh0,
             const float* __restrict__ bih0, const float* __restrict__ bhh0,
             const float* __restrict__ Wih1, const float* __restrict__ Whh1,
             const float* __restrict__ bih1, const float* __restrict__ bhh1,
             const float* __restrict__ Whead, const float* __restrict__ bhead_p,
             const int* __restrict__ lengths, const int* __restrict__ revp,
             float* __restrict__ out)
{
  __shared__ unsigned short XB[16][XBS];
  __shared__ float dpart[NWAVE][16];

  const int tid = threadIdx.x;
  const int l   = tid & 63;
  const int w   = tid >> 6;        // wave id: owns hidden units [8w, 8w+8)
  const int g   = l >> 4;          // lanegroup
  const int r16 = l & 15;          // batch slot (0..7 real)
  const int b0  = blockIdx.x * BQ;
  const int rev = revp[0];

  { // zero LDS
    unsigned int* p = (unsigned int*)&XB[0][0];
    for (int i = tid; i < 16*XBS/2; i += 512) p[i] = 0u;
    if (tid < NWAVE*16) ((float*)dpart)[tid] = 0.f;
  }

  // ---- weights -> registers as MFMA A-fragments (permuted gate rows) ----
  // wave-w rows p in [32w,32w+32): tile tau=t1, in-tile row = 2u + t0,
  // gate t = 2*tau + t0, source row j = 64*t + 8*w + u.
  bf16x8 A0[2][3], A1[2][4];
  {
    const int u  = r16 >> 1;
    const int t0 = r16 & 1;
#pragma unroll
    for (int tau = 0; tau < 2; ++tau){
      const int j = 64*(2*tau + t0) + 8*w + u;
#pragma unroll
      for (int k = 0; k < 3; ++k){      // L0: [Whh0(64) | Wih0 cols 0..5 | 0pad]
        bf16x8 a;
#pragma unroll
        for (int e = 0; e < 8; ++e){
          const int c = 32*k + 8*g + e;
          float v = 0.f;
          if (c < 64) v = Whh0[j*64 + c];
          else if (c < 70) v = Wih0[j*6 + (c-64)];
          a[e] = (short)f2bf(v);
        }
        A0[tau][k] = a;
      }
#pragma unroll
      for (int k = 0; k < 4; ++k){      // L1: [Wih1(64) | Whh1(64)]
        bf16x8 a;
#pragma unroll
        for (int e = 0; e < 8; ++e){
          const int c = 32*k + 8*g + e;
          const float v = (c < 64) ? Wih1[j*64 + c] : Whh1[j*64 + (c-64)];
          a[e] = (short)f2bf(v);
        }
        A1[tau][k] = a;
      }
    }
  }

  // act-side per-lane constants: hidden u = 2g + jslot
  float bp0[4][2], bp1[4][2], wx[4][2];
#pragma unroll
  for (int t4 = 0; t4 < 4; ++t4){
#pragma unroll
    for (int j = 0; j < 2; ++j){
      const int jj = 64*t4 + 8*w + 2*g + j;
      const float sc = (t4 == 2) ? 2.8853900817779268f : -1.4426950408889634f;
      bp0[t4][j] = sc * (bih0[jj] + bhh0[jj]);
      bp1[t4][j] = sc * (bih1[jj] + bhh1[jj]);
      wx[t4][j]  = Wih0[jj*6 + 5];     // h_d column of W_ih0 (done on VALU)
    }
  }
  const float wh0 = Whead[8*w + 2*g + 0];
  const float wh1 = Whead[8*w + 2*g + 1];
  const float bhead = bhead_p[0];
  const int   lenb  = lengths[b0 + (r16 & 7)];

  __syncthreads();

  // x prefetch pipeline: x(t) lives in buf t&1; wave1 lanes 0..7 manage it.
  float xr0=0,xr1=0,xr2=0,xr3=0,xr4=0;
  const bool xload = (w == 1) && (l < 8);
  if (xload){
    const int t0p = rev ? (L_SEQ-1) : 0;
    const float4 v = *(const float4*)(dP + ((size_t)(b0+l)*L_SEQ + t0p)*4);
    const float ev = eps[(size_t)(b0+l)*L_SEQ + t0p];
    unsigned int* dst = (unsigned int*)&XB[l][256];
    dst[0] = cvtpk(v.x, v.y);
    dst[1] = cvtpk(v.z, v.w);
    XB[l][256+4] = (unsigned short)cvtpk(ev, ev);
    const int t1p = rev ? (L_SEQ-2) : 1;
    const float4 v1 = *(const float4*)(dP + ((size_t)(b0+l)*L_SEQ + t1p)*4);
    xr0=v1.x; xr1=v1.y; xr2=v1.z; xr3=v1.w;
    xr4 = eps[(size_t)(b0+l)*L_SEQ + t1p];
  }
  __syncthreads();

  float c00=0,c01=0,c10=0,c11=0, h_d=0;
  const unsigned short* Brow = &XB[r16][0];

  for (int t = 0; t < L_SEQ; ++t){
    const int par = t & 1;
    const int tp  = rev ? (L_SEQ-1-t) : t;
    const bool act = tp < lenb;
    const bool ap  = (t == 0) || ((rev ? (L_SEQ - t) : (t-1)) < lenb); // prev step active?

    // ---- P1: L0 MFMAs + hh1 half of L1 (only needs h1_prev) ----
    f32x4 acc0a={0,0,0,0}, acc0b={0,0,0,0}, acc1a={0,0,0,0}, acc1b={0,0,0,0};
    {
      const int hb  = 64*(par^1);            // h0(t-1)
      const int h1b = 128 + 64*(par^1);      // h1(t-1)
      bf16x8 bk0 = *(const bf16x8*)(Brow + hb + 8*g);
      bf16x8 bk1 = *(const bf16x8*)(Brow + hb + 32 + 8*g);
      bf16x8 bx  = *(const bf16x8*)(Brow + 256 + 32*par + 8*g);
      bf16x8 bh2 = *(const bf16x8*)(Brow + h1b + 8*g);
      bf16x8 bh3 = *(const bf16x8*)(Brow + h1b + 32 + 8*g);
      bk0 = maskz(bk0, ap); bk1 = maskz(bk1, ap);   // new_hs = where(active,...,0)
      bh2 = maskz(bh2, ap); bh3 = maskz(bh3, ap);
      acc0a = __builtin_amdgcn_mfma_f32_16x16x32_bf16(A0[0][0], bk0, acc0a,0,0,0);
      acc0b = __builtin_amdgcn_mfma_f32_16x16x32_bf16(A0[1][0], bk0, acc0b,0,0,0);
      acc0a = __builtin_amdgcn_mfma_f32_16x16x32_bf16(A0[0][1], bk1, acc0a,0,0,0);
      acc0b = __builtin_amdgcn_mfma_f32_16x16x32_bf16(A0[1][1], bk1, acc0b,0,0,0);
      acc0a = __builtin_amdgcn_mfma_f32_16x16x32_bf16(A0[0][2], bx,  acc0a,0,0,0);
      acc0b = __builtin_amdgcn_mfma_f32_16x16x32_bf16(A0[1][2], bx,  acc0b,0,0,0);
      acc1a = __builtin_amdgcn_mfma_f32_16x16x32_bf16(A1[0][2], bh2, acc1a,0,0,0);
      acc1b = __builtin_amdgcn_mfma_f32_16x16x32_bf16(A1[1][2], bh2, acc1b,0,0,0);
      acc1a = __builtin_amdgcn_mfma_f32_16x16x32_bf16(A1[0][3], bh3, acc1a,0,0,0);
      acc1b = __builtin_amdgcn_mfma_f32_16x16x32_bf16(A1[1][3], bh3, acc1b,0,0,0);
    }
    // ---- P2: act0 -> write raw h0 to buf par; wave1 writes x(t+1), loads x(t+2) ----
    {
      float h0 = cell_act(__builtin_fmaf(wx[0][0],h_d,acc0a[0]),
                          __builtin_fmaf(wx[1][0],h_d,acc0a[1]),
                          __builtin_fmaf(wx[2][0],h_d,acc0b[0]),
                          __builtin_fmaf(wx[3][0],h_d,acc0b[1]),
                          bp0[0][0],bp0[1][0],bp0[2][0],bp0[3][0], c00, act);
      float h1 = cell_act(__builtin_fmaf(wx[0][1],h_d,acc0a[2]),
                          __builtin_fmaf(wx[1][1],h_d,acc0a[3]),
                          __builtin_fmaf(wx[2][1],h_d,acc0b[2]),
                          __builtin_fmaf(wx[3][1],h_d,acc0b[3]),
                          bp0[0][1],bp0[1][1],bp0[2][1],bp0[3][1], c01, act);
      *(unsigned int*)&XB[r16][64*par + 8*w + 2*g] = cvtpk(h0, h1);
      if (xload){
        unsigned int* dst = (unsigned int*)&XB[l][256 + 32*(par^1)];
        dst[0] = cvtpk(xr0, xr1);
        dst[1] = cvtpk(xr2, xr3);
        XB[l][256 + 32*(par^1) + 4] = (unsigned short)cvtpk(xr4, xr4);
        int ts = t + 2;
        int tpn = rev ? (L_SEQ-1-ts) : ts;
        tpn = tpn < 0 ? 0 : (tpn >= L_SEQ ? L_SEQ-1 : tpn);
        const float4 v = *(const float4*)(dP + ((size_t)(b0+l)*L_SEQ + tpn)*4);
        xr0=v.x; xr1=v.y; xr2=v.z; xr3=v.w;
        xr4 = eps[(size_t)(b0+l)*L_SEQ + tpn];
      }
    }
    __syncthreads();   // B2: h0(t) + x(t+1) visible
    // ---- P3: ih1 half of L1 (needs raw h0(t)) ----
    {
      const int h0b = 64*par;
      bf16x8 bk0 = *(const bf16x8*)(Brow + h0b + 8*g);
      bf16x8 bk1 = *(const bf16x8*)(Brow + h0b + 32 + 8*g);
      acc1a = __builtin_amdgcn_mfma_f32_16x16x32_bf16(A1[0][0], bk0, acc1a,0,0,0);
      acc1b = __builtin_amdgcn_mfma_f32_16x16x32_bf16(A1[1][0], bk0, acc1b,0,0,0);
      acc1a = __builtin_amdgcn_mfma_f32_16x16x32_bf16(A1[0][1], bk1, acc1a,0,0,0);
      acc1b = __builtin_amdgcn_mfma_f32_16x16x32_bf16(A1[1][1], bk1, acc1b,0,0,0);
    }
    // ---- P4: act1 (raw h1 feeds head), write raw h1, head partial reduce ----
    {
      float h0 = cell_act(acc1a[0],acc1a[1],acc1b[0],acc1b[1],
                          bp1[0][0],bp1[1][0],bp1[2][0],bp1[3][0], c10, act);
      float h1 = cell_act(acc1a[2],acc1a[3],acc1b[2],acc1b[3],
                          bp1[0][1],bp1[1][1],bp1[2][1],bp1[3][1], c11, act);
      *(unsigned int*)&XB[r16][128 + 64*par + 8*w + 2*g] = cvtpk(h0, h1);
      float s = __builtin_fmaf(wh0, h0, wh1*h1);
      s += __shfl_xor(s, 16, 64);
      s += __shfl_xor(s, 32, 64);
      if (l < 16) dpart[w][l] = s;
    }
    __syncthreads();   // B4: h1(t) + dpart visible
    // ---- P5: delta, h_d update (replicated in every wave), outputs ----
    {
      float dsum = bhead;
#pragma unroll
      for (int ww = 0; ww < NWAVE; ++ww) dsum += dpart[ww][r16];
      const float h_prev = h_d;
      if (act) h_d += dsum;            // where(active, h_d+delta, h_d)
      if (w == 0 && l < 8){
        const int bi = b0 + l;
        out[(size_t)bi*L_SEQ + tp] = h_prev;                                // h_seq
        out[(size_t)B_TOT*L_SEQ + (size_t)bi*L_SEQ + tp] = dsum;            // d_seq
      }
    }
  }
}

extern "C" void kernel_launch(void* const* d_in, const int* in_sizes, int n_in,
                              void* d_out, int out_size, void* d_ws, size_t ws_size,
                              hipStream_t stream) {
  (void)in_sizes; (void)n_in; (void)d_ws; (void)ws_size; (void)out_size;
  dh_lstm<<<dim3(NBLK), dim3(512), 0, stream>>>(
      (const float*)d_in[0],  (const float*)d_in[1],
      (const float*)d_in[2],  (const float*)d_in[3],
      (const float*)d_in[4],  (const float*)d_in[5],
      (const float*)d_in[6],  (const float*)d_in[7],
      (const float*)d_in[8],  (const float*)d_in[9],
      (const float*)d_in[10], (const float*)d_in[11],
      (const int*)d_in[12],   (const int*)d_in[13],
      (float*)d_out);
}